// Round 6
// baseline (285.496 us; speedup 1.0000x reference)
//
#include <hip/hip_runtime.h>
#include <hip/hip_cooperative_groups.h>
#include <stdint.h>

namespace cg = cooperative_groups;

#define N_ANCH 102400
#define FMP 320
#define K_TOP 1000
#define NMS_T 0.6f
#define SC_CLAMP 6.907755278982137f
#define IMGF 1280.0f
#define NBINS 16384   // scores in (0,1) => float bits>>16 < 0x4000
#define NBLK 256
#define NTHR 1024

// ---- workspace layout (bytes) ----
#define OFF_SCORES   0u          // f32[102400]
#define OFF_LABELS   409600u     // u32[102400]
#define OFF_HIST     819200u     // u32[16384]
#define OFF_META     884736u     // u32[64]: [0]=cutoff [2]=cand ctr
#define OFF_KEYS     884992u     // u64[4096]
#define OFF_BOXES    917760u     // f32[4000]
#define OFF_LAB1K    933760u     // u32[1000]
#define OFF_MASK     937760u     // u64[16000]
#define OFF_DIAG     1065760u    // u64[1024]

__device__ __forceinline__ float sigf(float x) {
    return 1.0f / (1.0f + expf(-x));
}

__global__ __launch_bounds__(NTHR) void k_all(const float* __restrict__ hmp,
                                              const float* __restrict__ reg,
                                              const float* __restrict__ iou,
                                              float* __restrict__ out,
                                              float* __restrict__ scores,
                                              uint32_t* __restrict__ labels,
                                              uint32_t* __restrict__ hist,
                                              uint32_t* __restrict__ meta,
                                              uint64_t* __restrict__ keys,
                                              float* __restrict__ boxes,
                                              uint32_t* __restrict__ lab1k,
                                              uint64_t* __restrict__ mask,
                                              uint64_t* __restrict__ diag) {
    __shared__ __align__(16) unsigned char smraw[65536];
    uint32_t* lh = (uint32_t*)smraw;          // 16384 bins (64 KB)
    uint64_t* sk = (uint64_t*)smraw;          // 4096 keys (32 KB), phase E
    cg::grid_group grid = cg::this_grid();

    const int tid  = threadIdx.x;
    const int blk  = blockIdx.x;
    const int gtid = blk * NTHR + tid;
    const int lane = tid & 63;

    // ================= Phase A: zero + scores/argmax + LDS histogram =================
    if (gtid < NBINS) hist[gtid] = 0u;
    if (gtid >= NBINS && gtid < NBINS + 64) meta[gtid - NBINS] = 0u;
    for (int i = tid; i < NBINS; i += NTHR) lh[i] = 0u;
    __syncthreads();
#pragma unroll
    for (int it = 0; it < 2; ++it) {
        int w = gtid + it * (NBLK * NTHR);
        if (w < N_ANCH * 4) {
            int a = w >> 2;
            int q = w & 3;
            float si = sigf(iou[a]);
            const float4* row4 = (const float4*)hmp + (size_t)a * 20 + q;
            float4 v[5];
#pragma unroll
            for (int j = 0; j < 5; ++j) v[j] = row4[j * 4];
            float best = -1.0f;
            int bc = 0;
#pragma unroll
            for (int j = 0; j < 5; ++j) {
                int cb = j * 16 + q * 4;
                float f;
                f = sqrtf(sigf(v[j].x) * si); if (f > best) { best = f; bc = cb; }
                f = sqrtf(sigf(v[j].y) * si); if (f > best) { best = f; bc = cb + 1; }
                f = sqrtf(sigf(v[j].z) * si); if (f > best) { best = f; bc = cb + 2; }
                f = sqrtf(sigf(v[j].w) * si); if (f > best) { best = f; bc = cb + 3; }
            }
#pragma unroll
            for (int off = 1; off <= 2; off <<= 1) {
                float of = __shfl_xor(best, off);
                int   oc = __shfl_xor(bc, off);
                if (of > best || (of == best && oc < bc)) { best = of; bc = oc; }
            }
            if (q == 0) {
                scores[a] = best;
                labels[a] = (uint32_t)bc;
                atomicAdd(&lh[__float_as_uint(best) >> 16], 1u);
            }
        }
    }
    grid.sync();   // ---- sync1: scores + local hists + global zero complete

    // ================= Phase B: flush LDS hist -> global =================
    for (int i = tid; i < NBINS; i += NTHR) {
        uint32_t c = lh[i];
        if (c) atomicAdd(&hist[i], c);
    }
    grid.sync();   // ---- sync2: global hist complete

    // ================= Phase C: cutoff (block 0) =================
    if (blk == 0) {
        uint32_t s = 0;
#pragma unroll
        for (int b = 0; b < 16; ++b) s += hist[tid * 16 + b];
        lh[tid] = s;
        __syncthreads();
        for (int off = 1; off < NTHR; off <<= 1) {
            uint32_t v = lh[tid] + ((tid + off < NTHR) ? lh[tid + off] : 0u);
            __syncthreads();
            lh[tid] = v;
            __syncthreads();
        }
        uint32_t inc   = lh[tid];
        uint32_t above = (tid < NTHR - 1) ? lh[tid + 1] : 0u;
        if (above < K_TOP && inc >= K_TOP) {
            uint32_t loc[16];
#pragma unroll
            for (int b = 0; b < 16; ++b) loc[b] = hist[tid * 16 + b];
            uint32_t cnt = above;
            for (int b = 15; b >= 0; --b) {
                cnt += loc[b];
                if (cnt >= K_TOP) { meta[0] = (uint32_t)(tid * 16 + b); break; }
            }
        }
    }
    grid.sync();   // ---- sync3: cutoff ready

    // ================= Phase D: collect candidates (block-aggregated) =================
    if (tid == 0) lh[0] = 0u;
    __syncthreads();
    uint32_t mypos = 0, mybits = 0;
    bool cand = false;
    if (gtid < N_ANCH) {
        mybits = __float_as_uint(scores[gtid]);
        cand = (mybits >> 16) >= meta[0];
        if (cand) mypos = atomicAdd(&lh[0], 1u);
    }
    __syncthreads();
    if (tid == 0 && lh[0]) lh[1] = atomicAdd(&meta[2], lh[0]);
    __syncthreads();
    if (cand) {
        uint32_t pos = lh[1] + mypos;
        if (pos < 4096)
            keys[pos] = ((uint64_t)mybits << 32) | (uint64_t)(0xFFFFFFFFu - (uint32_t)gtid);
    }
    grid.sync();   // ---- sync4: keys complete

    // ================= Phase E: rank (one wave per candidate) + decode =================
    {
        uint32_t M = meta[2];
        if (M > 4096u) M = 4096u;
        for (uint32_t i = tid; i < M; i += NTHR) sk[i] = keys[i];
        __syncthreads();
        int wg = blk * 16 + (tid >> 6);
        if ((uint32_t)wg < M) {
            uint64_t mykey = sk[wg];
            uint32_t rank = 0;
            for (uint32_t j = lane; j < M; j += 64) rank += (sk[j] > mykey) ? 1u : 0u;
#pragma unroll
            for (int off = 32; off; off >>= 1) rank += __shfl_xor(rank, off);
            if (lane == 0 && rank < K_TOP) {
                int t = (int)rank;
                uint32_t sbits = (uint32_t)(mykey >> 32);
                uint32_t idx   = 0xFFFFFFFFu - (uint32_t)(mykey & 0xFFFFFFFFull);
                float score = __uint_as_float(sbits);
                uint32_t lab = labels[idx];
                out[t]         = score;
                out[K_TOP + t] = (float)lab;
                lab1k[t]       = lab;
                float ax = (float)(idx % FMP);
                float ay = (float)(idx / FMP);
                float4 rr = ((const float4*)reg)[idx];
                float e0 = expf(fminf(rr.x, SC_CLAMP));
                float e1 = expf(fminf(rr.y, SC_CLAMP));
                float e2 = expf(fminf(rr.z, SC_CLAMP));
                float e3 = expf(fminf(rr.w, SC_CLAMP));
                float x1 = fminf(fmaxf((ax - e0) * 4.0f / IMGF, 0.0f), 1.0f);
                float y1 = fminf(fmaxf((ay - e1) * 4.0f / IMGF, 0.0f), 1.0f);
                float x2 = fminf(fmaxf((ax + e2) * 4.0f / IMGF, 0.0f), 1.0f);
                float y2 = fminf(fmaxf((ay + e3) * 4.0f / IMGF, 0.0f), 1.0f);
                out[2 * K_TOP + t * 4 + 0] = x1;
                out[2 * K_TOP + t * 4 + 1] = y1;
                out[2 * K_TOP + t * 4 + 2] = x2;
                out[2 * K_TOP + t * 4 + 3] = y2;
                boxes[t * 4 + 0] = x1;
                boxes[t * 4 + 1] = y1;
                boxes[t * 4 + 2] = x2;
                boxes[t * 4 + 3] = y2;
            }
        }
    }
    grid.sync();   // ---- sync5: boxes/labels ready

    // ================= Phase F: suppress masks (one wave per row) =================
    {
        int wg = blk * 16 + (tid >> 6);
        if (wg < 1024) {
            if (wg < K_TOP) {
                int i = wg;
                float4 bi = ((const float4*)boxes)[i];
                uint32_t li = lab1k[i];
                float areai = (bi.z - bi.x) * (bi.w - bi.y);
                int iw = i >> 6;
                uint64_t dw = 0ull;
#pragma unroll
                for (int w = 0; w < 16; ++w) {
                    int j = w * 64 + lane;
                    bool sup = false;
                    if (j < K_TOP && j > i) {
                        float4 bj = ((const float4*)boxes)[j];
                        float areaj = (bj.z - bj.x) * (bj.w - bj.y);
                        float xx1 = fmaxf(bi.x, bj.x);
                        float yy1 = fmaxf(bi.y, bj.y);
                        float xx2 = fminf(bi.z, bj.z);
                        float yy2 = fminf(bi.w, bj.w);
                        float ww = fmaxf(1e-10f, xx2 - xx1);
                        float hh = fmaxf(1e-10f, yy2 - yy1);
                        float inter = ww * hh;
                        float iouv = inter / (areai + areaj - inter + 1e-10f);
                        sup = (iouv > NMS_T) && (li == lab1k[j]);
                    }
                    unsigned long long m = __ballot(sup);
                    if (lane == 0) mask[(size_t)i * 16 + w] = (uint64_t)m;
                    if (w == iw) dw = (uint64_t)m;
                }
                if (lane == 0) diag[i] = dw;
            } else {
                if (lane == 0) diag[wg] = 0ull;
            }
        }
    }
    grid.sync();   // ---- sync6: masks + diag ready

    // ================= Phase G: greedy scan (block 0, wave 0) =================
    if (blk == 0 && tid < 64) {
        int q = lane >> 4, wrd = lane & 15;
        uint64_t remv = 0ull;
        uint64_t dcur = diag[lane];
        for (int g = 0; g < 16; ++g) {
            uint64_t dnxt = (g < 15) ? diag[64 * (g + 1) + lane] : 0ull;
            uint64_t bun[16];
            if (g < 15) {
#pragma unroll
                for (int r4 = 0; r4 < 16; ++r4)
                    bun[r4] = mask[(size_t)(64 * g + 4 * r4 + q) * 16 + wrd];
            }
            uint32_t dlo = 0, dhi = 0;
#pragma unroll
            for (int qq = 0; qq < 4; ++qq) {
                dlo |= __builtin_amdgcn_readlane((uint32_t)remv, qq * 16 + g);
                dhi |= __builtin_amdgcn_readlane((uint32_t)(remv >> 32), qq * 16 + g);
            }
            uint64_t D = ((uint64_t)dhi << 32) | dlo;
#pragma unroll
            for (int b = 0; b < 64; ++b) {
                uint32_t tlo = __builtin_amdgcn_readlane((uint32_t)dcur, b);
                uint32_t thi = __builtin_amdgcn_readlane((uint32_t)(dcur >> 32), b);
                uint64_t T = ((uint64_t)thi << 32) | tlo;
                uint64_t sel = ((D >> b) & 1ull) - 1ull;   // ~0 if row kept
                D |= T & sel;
            }
            uint64_t keepg = ~D;
            int j = g * 64 + lane;
            if (j < K_TOP) out[6 * K_TOP + j] = (float)((keepg >> lane) & 1ull);
            if (g < 15) {
#pragma unroll
                for (int r4 = 0; r4 < 16; ++r4) {
                    uint32_t kb = (uint32_t)(keepg >> (4 * r4 + q)) & 1u;
                    uint64_t mm = 0ull - (uint64_t)kb;
                    remv |= bun[r4] & mm;
                }
            }
            dcur = dnxt;
        }
    }
}

extern "C" void kernel_launch(void* const* d_in, const int* in_sizes, int n_in,
                              void* d_out, int out_size, void* d_ws, size_t ws_size,
                              hipStream_t stream) {
    const float* hmp = (const float*)d_in[0];
    const float* reg = (const float*)d_in[1];
    const float* iou = (const float*)d_in[2];
    float* out = (float*)d_out;
    char* ws = (char*)d_ws;

    float*    scores = (float*)(ws + OFF_SCORES);
    uint32_t* labels = (uint32_t*)(ws + OFF_LABELS);
    uint32_t* hist   = (uint32_t*)(ws + OFF_HIST);
    uint32_t* meta   = (uint32_t*)(ws + OFF_META);
    uint64_t* keys   = (uint64_t*)(ws + OFF_KEYS);
    float*    boxes  = (float*)(ws + OFF_BOXES);
    uint32_t* lab1k  = (uint32_t*)(ws + OFF_LAB1K);
    uint64_t* mask   = (uint64_t*)(ws + OFF_MASK);
    uint64_t* diag   = (uint64_t*)(ws + OFF_DIAG);

    void* args[] = { (void*)&hmp, (void*)&reg, (void*)&iou, (void*)&out,
                     (void*)&scores, (void*)&labels, (void*)&hist, (void*)&meta,
                     (void*)&keys, (void*)&boxes, (void*)&lab1k, (void*)&mask,
                     (void*)&diag };
    hipLaunchCooperativeKernel((const void*)k_all, dim3(NBLK), dim3(NTHR),
                               args, 0, stream);
}

// Round 7
// 156.527 us; speedup vs baseline: 1.8239x; 1.8239x over previous
//
#include <hip/hip_runtime.h>
#include <stdint.h>

#define N_ANCH 102400
#define FMP 320
#define K_TOP 1000
#define NMS_T 0.6f
#define SC_CLAMP 6.907755278982137f
#define IMGF 1280.0f
#define NBINS 16384   // scores in (0,1) => float bits>>16 < 0x4000

// ---- workspace layout (bytes) ----
#define OFF_SCORES   0u          // f32[102400]
#define OFF_LABELS   409600u     // u32[102400]
#define OFF_HIST     819200u     // u32[16384]
#define OFF_META     884736u     // u32[64]: [0]=cutoff [2]=cand ctr [8]=hist arrive
#define OFF_KEYS     884992u     // u64[4096]
#define OFF_BOXES    917760u     // f32[4000]
#define OFF_LAB1K    933760u     // u32[1000]
#define OFF_MASK     937760u     // u64[16000]
#define OFF_DIAG     1065760u    // u64[1024]

__device__ __forceinline__ float sigf(float x) {
    return 1.0f / (1.0f + expf(-x));
}

// ---------------- K1: scores+argmax; fused zeroing of hist/meta/diag ----------------
__global__ __launch_bounds__(256) void k_scores(const float* __restrict__ hmp,
                                                const float* __restrict__ iou,
                                                float* __restrict__ scores,
                                                uint32_t* __restrict__ labels,
                                                uint32_t* __restrict__ hist,
                                                uint32_t* __restrict__ meta,
                                                uint64_t* __restrict__ diag) {
    int blk = blockIdx.x;
    if (blk < 64) {
        hist[blk * 256 + threadIdx.x] = 0u;
    } else if (blk == 64) {
        if (threadIdx.x < 64) meta[threadIdx.x] = 0u;
#pragma unroll
        for (int k = 0; k < 4; ++k) diag[threadIdx.x * 4 + k] = 0ull;
    }
    int gid = blk * 256 + threadIdx.x;
    int a = gid >> 2;
    int q = gid & 3;
    float si = sigf(iou[a]);
    const float4* row4 = (const float4*)hmp + (size_t)a * 20 + q;
    float4 v[5];
#pragma unroll
    for (int j = 0; j < 5; ++j) v[j] = row4[j * 4];
    float best = -1.0f;
    int bc = 0;
#pragma unroll
    for (int j = 0; j < 5; ++j) {
        int cb = j * 16 + q * 4;
        float f;
        f = sqrtf(sigf(v[j].x) * si); if (f > best) { best = f; bc = cb; }
        f = sqrtf(sigf(v[j].y) * si); if (f > best) { best = f; bc = cb + 1; }
        f = sqrtf(sigf(v[j].z) * si); if (f > best) { best = f; bc = cb + 2; }
        f = sqrtf(sigf(v[j].w) * si); if (f > best) { best = f; bc = cb + 3; }
    }
#pragma unroll
    for (int off = 1; off <= 2; off <<= 1) {
        float of = __shfl_xor(best, off);
        int   oc = __shfl_xor(bc, off);
        if (of > best || (of == best && oc < bc)) { best = of; bc = oc; }
    }
    if (q == 0) {
        scores[a] = best;
        labels[a] = (uint32_t)bc;
    }
}

// ---------------- K2: LDS-private histogram; last of 64 blocks finds cutoff ----------------
__global__ __launch_bounds__(1024) void k_hist(const float* __restrict__ scores,
                                               uint32_t* __restrict__ hist,
                                               uint32_t* __restrict__ meta) {
    __shared__ uint32_t lh[NBINS];
    __shared__ int lastFlag;
    for (int i = threadIdx.x; i < NBINS; i += 1024) lh[i] = 0u;
    __syncthreads();
    int base = blockIdx.x * 1600;
    for (int k = threadIdx.x; k < 1600; k += 1024) {
        uint32_t bin = __float_as_uint(scores[base + k]) >> 16;
        atomicAdd(&lh[bin], 1u);
    }
    __syncthreads();
    for (int i = threadIdx.x; i < NBINS; i += 1024) {
        uint32_t c = lh[i];
        if (c) atomicAdd(&hist[i], c);
    }
    __threadfence();
    __syncthreads();
    if (threadIdx.x == 0) lastFlag = (atomicAdd(&meta[8], 1u) == 63u);
    __syncthreads();
    if (!lastFlag) return;
    __threadfence();
    int t = threadIdx.x;
    uint32_t s = 0;
#pragma unroll
    for (int b = 0; b < 16; ++b) s += hist[t * 16 + b];
    lh[t] = s;
    __syncthreads();
    for (int off = 1; off < 1024; off <<= 1) {
        uint32_t v = lh[t] + ((t + off < 1024) ? lh[t + off] : 0u);
        __syncthreads();
        lh[t] = v;
        __syncthreads();
    }
    uint32_t inc   = lh[t];
    uint32_t above = (t < 1023) ? lh[t + 1] : 0u;
    if (above < K_TOP && inc >= K_TOP) {
        uint32_t loc[16];
#pragma unroll
        for (int b = 0; b < 16; ++b) loc[b] = hist[t * 16 + b];
        uint32_t cnt = above;
        for (int b = 15; b >= 0; --b) {
            cnt += loc[b];
            if (cnt >= K_TOP) { meta[0] = (uint32_t)(t * 16 + b); break; }
        }
    }
}

// ---------------- K3: collect candidates, block-aggregated append ----------------
__global__ __launch_bounds__(256) void k_collect(const float* __restrict__ scores,
                                                 uint32_t* __restrict__ meta,
                                                 uint64_t* __restrict__ keys) {
    __shared__ uint32_t cnt, base;
    if (threadIdx.x == 0) cnt = 0u;
    __syncthreads();
    int i = blockIdx.x * 256 + threadIdx.x;
    uint32_t bits = __float_as_uint(scores[i]);
    bool cand = (bits >> 16) >= meta[0];
    uint32_t pos = 0;
    if (cand) pos = atomicAdd(&cnt, 1u);
    __syncthreads();
    if (threadIdx.x == 0 && cnt) base = atomicAdd(&meta[2], cnt);
    __syncthreads();
    if (cand) {
        uint32_t p = base + pos;
        if (p < 4096u)
            keys[p] = ((uint64_t)bits << 32) | (uint64_t)(0xFFFFFFFFu - (uint32_t)i);
    }
}

// ---------------- K4: rank (wave per candidate) + decode epilogue ----------------
__global__ __launch_bounds__(1024) void k_rank(const uint64_t* __restrict__ keys,
                                               const uint32_t* __restrict__ meta,
                                               const uint32_t* __restrict__ labels,
                                               const float* __restrict__ reg,
                                               float* __restrict__ out,
                                               float* __restrict__ boxes,
                                               uint32_t* __restrict__ lab1k) {
    __shared__ uint64_t sk[4096];
    uint32_t M = meta[2];
    if (M > 4096u) M = 4096u;
    if ((uint32_t)(blockIdx.x * 16) >= M) return;
    for (uint32_t i = threadIdx.x; i < M; i += 1024) sk[i] = keys[i];
    __syncthreads();
    int lane = threadIdx.x & 63;
    int wg = blockIdx.x * 16 + (threadIdx.x >> 6);
    if ((uint32_t)wg >= M) return;
    uint64_t mykey = sk[wg];
    uint32_t rank = 0;
    for (uint32_t j = lane; j < M; j += 64) rank += (sk[j] > mykey) ? 1u : 0u;
#pragma unroll
    for (int off = 32; off; off >>= 1) rank += __shfl_xor(rank, off);
    if (lane != 0 || rank >= K_TOP) return;
    int t = (int)rank;
    uint32_t sbits = (uint32_t)(mykey >> 32);
    uint32_t idx   = 0xFFFFFFFFu - (uint32_t)(mykey & 0xFFFFFFFFull);
    float score = __uint_as_float(sbits);
    uint32_t lab = labels[idx];
    out[t]         = score;
    out[K_TOP + t] = (float)lab;
    lab1k[t]       = lab;
    float ax = (float)(idx % FMP);
    float ay = (float)(idx / FMP);
    float4 rr = ((const float4*)reg)[idx];
    float e0 = expf(fminf(rr.x, SC_CLAMP));
    float e1 = expf(fminf(rr.y, SC_CLAMP));
    float e2 = expf(fminf(rr.z, SC_CLAMP));
    float e3 = expf(fminf(rr.w, SC_CLAMP));
    float x1 = fminf(fmaxf((ax - e0) * 4.0f / IMGF, 0.0f), 1.0f);
    float y1 = fminf(fmaxf((ay - e1) * 4.0f / IMGF, 0.0f), 1.0f);
    float x2 = fminf(fmaxf((ax + e2) * 4.0f / IMGF, 0.0f), 1.0f);
    float y2 = fminf(fmaxf((ay + e3) * 4.0f / IMGF, 0.0f), 1.0f);
    out[2 * K_TOP + t * 4 + 0] = x1;
    out[2 * K_TOP + t * 4 + 1] = y1;
    out[2 * K_TOP + t * 4 + 2] = x2;
    out[2 * K_TOP + t * 4 + 3] = y2;
    boxes[t * 4 + 0] = x1;
    boxes[t * 4 + 1] = y1;
    boxes[t * 4 + 2] = x2;
    boxes[t * 4 + 3] = y2;
}

// ---------------- K5: suppress masks, one wave per row (63 x 1024) ----------------
__global__ __launch_bounds__(1024) void k_mask(const float* __restrict__ boxes,
                                               const uint32_t* __restrict__ lab1k,
                                               uint64_t* __restrict__ mask,
                                               uint64_t* __restrict__ diag) {
    int r = blockIdx.x * 16 + (threadIdx.x >> 6);
    int lane = threadIdx.x & 63;
    if (r >= K_TOP) return;
    float4 bi = ((const float4*)boxes)[r];
    uint32_t li = lab1k[r];
    float areai = (bi.z - bi.x) * (bi.w - bi.y);
    int iw = r >> 6;
    uint64_t dw = 0ull;
#pragma unroll
    for (int w = 0; w < 16; ++w) {
        int j = w * 64 + lane;
        bool sup = false;
        if (j < K_TOP && j > r) {
            float4 bj = ((const float4*)boxes)[j];
            float areaj = (bj.z - bj.x) * (bj.w - bj.y);
            float xx1 = fmaxf(bi.x, bj.x);
            float yy1 = fmaxf(bi.y, bj.y);
            float xx2 = fminf(bi.z, bj.z);
            float yy2 = fminf(bi.w, bj.w);
            float ww = fmaxf(1e-10f, xx2 - xx1);
            float hh = fmaxf(1e-10f, yy2 - yy1);
            float inter = ww * hh;
            float iouv = inter / (areai + areaj - inter + 1e-10f);
            sup = (iouv > NMS_T) && (li == lab1k[j]);
        }
        unsigned long long m = __ballot(sup);
        if (lane == 0) mask[(size_t)r * 16 + w] = (uint64_t)m;
        if (w == iw) dw = (uint64_t)m;
    }
    if (lane == 0) diag[r] = dw;
}

// ---------------- K6: greedy scan, single wave, full register budget ----------------
// launch_bounds(64,1): VGPR cap ~512 so bun[16] (32 VGPRs) can't spill
// (R5/R6 fused versions compiled at VGPR=40 -> scratch -> 70-100us).
__global__ __launch_bounds__(64, 1) void k_scan(const uint64_t* __restrict__ mask,
                                                const uint64_t* __restrict__ diag,
                                                float* __restrict__ out) {
    int lane = threadIdx.x;
    int q = lane >> 4, wrd = lane & 15;
    uint64_t remv = 0ull;
    uint64_t dcur = diag[lane];
    for (int g = 0; g < 16; ++g) {
        uint64_t dnxt = (g < 15) ? diag[64 * (g + 1) + lane] : 0ull;
        uint64_t bun[16];
        if (g < 15) {
#pragma unroll
            for (int r4 = 0; r4 < 16; ++r4)
                bun[r4] = mask[(size_t)(64 * g + 4 * r4 + q) * 16 + wrd];
        }
        uint32_t dlo = 0, dhi = 0;
#pragma unroll
        for (int qq = 0; qq < 4; ++qq) {
            dlo |= __builtin_amdgcn_readlane((uint32_t)remv, qq * 16 + g);
            dhi |= __builtin_amdgcn_readlane((uint32_t)(remv >> 32), qq * 16 + g);
        }
        uint64_t D = ((uint64_t)dhi << 32) | dlo;
#pragma unroll
        for (int b = 0; b < 64; ++b) {
            uint32_t tlo = __builtin_amdgcn_readlane((uint32_t)dcur, b);
            uint32_t thi = __builtin_amdgcn_readlane((uint32_t)(dcur >> 32), b);
            uint64_t T = ((uint64_t)thi << 32) | tlo;
            uint64_t sel = ((D >> b) & 1ull) - 1ull;   // ~0 if row kept
            D |= T & sel;
        }
        uint64_t keepg = ~D;
        int j = g * 64 + lane;
        if (j < K_TOP) out[6 * K_TOP + j] = (float)((keepg >> lane) & 1ull);
        if (g < 15) {
#pragma unroll
            for (int r4 = 0; r4 < 16; ++r4) {
                uint32_t kb = (uint32_t)(keepg >> (4 * r4 + q)) & 1u;
                uint64_t mm = 0ull - (uint64_t)kb;
                remv |= bun[r4] & mm;
            }
        }
        dcur = dnxt;
    }
}

extern "C" void kernel_launch(void* const* d_in, const int* in_sizes, int n_in,
                              void* d_out, int out_size, void* d_ws, size_t ws_size,
                              hipStream_t stream) {
    const float* hmp = (const float*)d_in[0];
    const float* reg = (const float*)d_in[1];
    const float* iou = (const float*)d_in[2];
    float* out = (float*)d_out;
    char* ws = (char*)d_ws;

    float*    scores = (float*)(ws + OFF_SCORES);
    uint32_t* labels = (uint32_t*)(ws + OFF_LABELS);
    uint32_t* hist   = (uint32_t*)(ws + OFF_HIST);
    uint32_t* meta   = (uint32_t*)(ws + OFF_META);
    uint64_t* keys   = (uint64_t*)(ws + OFF_KEYS);
    float*    boxes  = (float*)(ws + OFF_BOXES);
    uint32_t* lab1k  = (uint32_t*)(ws + OFF_LAB1K);
    uint64_t* mask   = (uint64_t*)(ws + OFF_MASK);
    uint64_t* diag   = (uint64_t*)(ws + OFF_DIAG);

    k_scores<<<dim3(N_ANCH * 4 / 256), dim3(256), 0, stream>>>(hmp, iou, scores, labels, hist, meta, diag);
    k_hist<<<dim3(64), dim3(1024), 0, stream>>>(scores, hist, meta);
    k_collect<<<dim3(N_ANCH / 256), dim3(256), 0, stream>>>(scores, meta, keys);
    k_rank<<<dim3(256), dim3(1024), 0, stream>>>(keys, meta, labels, reg, out, boxes, lab1k);
    k_mask<<<dim3(63), dim3(1024), 0, stream>>>(boxes, lab1k, mask, diag);
    k_scan<<<dim3(1), dim3(64), 0, stream>>>(mask, diag, out);
}